// Round 7
// baseline (207.657 us; speedup 1.0000x reference)
//
#include <hip/hip_runtime.h>
#include <math.h>

#define NUM_C   1000
#define MOM     0.9f
#define EPS     1e-6f

// ---------------- kernel 1: per-row CE -> ce[row] ----------------
// R2's proven two-pass front-end (52.8us best), back-end changed: pure store
// of ce[row] instead of global atomics. No workspace init needed (every
// element written every call -> poison-safe, deterministic).
// R3 lesson: no __threadfence / last-block fusion (L2 writeback storm, 30x).
// R4-R6 lesson: don't touch the ce loop (online-softmax / no-max / 2-row ILP
// all regressed; pass is memory-system-limited at ~90% occupancy).
__global__ __launch_bounds__(256) void ce_kernel(const float* __restrict__ logits,
                                                 const int*   __restrict__ targets,
                                                 float* __restrict__ ce,
                                                 int n) {
    const int wave = threadIdx.x >> 6;
    const int lane = threadIdx.x & 63;
    const int row  = blockIdx.x * 4 + wave;
    if (row >= n) return;

    const int t  = targets[row];        // wave-uniform -> one line, broadcast
    const int tq = t >> 2;              // float4 index holding the target
    const int tc = t & 3;

    const float4* rp = reinterpret_cast<const float4*>(logits + (size_t)row * NUM_C);

    float4 v[4];
    float m = -INFINITY;
#pragma unroll
    for (int j = 0; j < 4; ++j) {
        int idx = j * 64 + lane;
        if (idx < 250) {
            v[j] = rp[idx];
            m = fmaxf(m, fmaxf(fmaxf(v[j].x, v[j].y), fmaxf(v[j].z, v[j].w)));
        }
    }
#pragma unroll
    for (int off = 32; off > 0; off >>= 1)
        m = fmaxf(m, __shfl_xor(m, off, 64));

    float s = 0.f;     // sum of exp(x - m)
    float lt = 0.f;    // logit at target (owning lane contributes)
#pragma unroll
    for (int j = 0; j < 4; ++j) {
        int idx = j * 64 + lane;
        if (idx < 250) {
            s += __expf(v[j].x - m);
            s += __expf(v[j].y - m);
            s += __expf(v[j].z - m);
            s += __expf(v[j].w - m);
            if (idx == tq) {
                lt = (tc == 0) ? v[j].x : (tc == 1) ? v[j].y
                   : (tc == 2) ? v[j].z : v[j].w;
            }
        }
    }
#pragma unroll
    for (int off = 32; off > 0; off >>= 1) {
        s  += __shfl_xor(s,  off, 64);
        lt += __shfl_xor(lt, off, 64);
    }

    if (lane == 0)
        ce[row] = (m + __logf(s)) - lt;   // -log_softmax at target
}

// ---------------- kernel 2: segment-reduce + EMA + weighted ratio ----------
// One block, 1024 threads. Reads (targets, ce) vectorized (512 KB total),
// accumulates per-class sums/counts in LDS via ds atomics, then:
//   out = [sum_c sums_c * w_c] / [sum_c cnt_c * w_c],  w_c = 1/(gm'_c + eps)
// Replaces the global-memset + global-atomics back-end (saves one dispatch
// and the memset->ce serialization bubble).
__global__ __launch_bounds__(1024) void finalize_kernel(const int*   __restrict__ targets,
                                                        const float* __restrict__ ce,
                                                        const float* __restrict__ gm_in,
                                                        float* __restrict__ out,
                                                        int n) {
    __shared__ float ls[NUM_C];
    __shared__ float lc[NUM_C];
    for (int c = threadIdx.x; c < NUM_C; c += 1024) { ls[c] = 0.f; lc[c] = 0.f; }
    __syncthreads();

    const int nq = n >> 2;            // n = 65536, divisible by 4
    const int4*   tp = reinterpret_cast<const int4*>(targets);
    const float4* cp = reinterpret_cast<const float4*>(ce);
    for (int i = threadIdx.x; i < nq; i += 1024) {
        int4   t4 = tp[i];
        float4 c4 = cp[i];
        atomicAdd(&ls[t4.x], c4.x); atomicAdd(&lc[t4.x], 1.0f);
        atomicAdd(&ls[t4.y], c4.y); atomicAdd(&lc[t4.y], 1.0f);
        atomicAdd(&ls[t4.z], c4.z); atomicAdd(&lc[t4.z], 1.0f);
        atomicAdd(&ls[t4.w], c4.w); atomicAdd(&lc[t4.w], 1.0f);
    }
    for (int i = (nq << 2) + (int)threadIdx.x; i < n; i += 1024) {  // tail (none for 65536)
        int t = targets[i];
        atomicAdd(&ls[t], ce[i]); atomicAdd(&lc[t], 1.0f);
    }
    __syncthreads();

    const int c = threadIdx.x;
    float a = 0.f, b = 0.f;
    if (c < NUM_C) {
        float cnt = lc[c];
        float s   = ls[c];
        float g   = gm_in[c];
        if (cnt > 0.f) {
            float cm = fabsf(s / fmaxf(cnt, 1.0f));
            g = MOM * g + (1.0f - MOM) * cm;
        }
        float w = 1.0f / (g + EPS);
        a = cnt * w;
        b = s * w;
    }
#pragma unroll
    for (int off = 32; off > 0; off >>= 1) {
        a += __shfl_xor(a, off, 64);
        b += __shfl_xor(b, off, 64);
    }
    __shared__ float sa[16], sb[16];
    const int lane = threadIdx.x & 63;
    const int wv   = threadIdx.x >> 6;
    if (lane == 0) { sa[wv] = a; sb[wv] = b; }
    __syncthreads();
    if (threadIdx.x == 0) {
        float A = 0.f, B = 0.f;
        for (int i = 0; i < 16; ++i) { A += sa[i]; B += sb[i]; }
        out[0] = B / A;
    }
}

extern "C" void kernel_launch(void* const* d_in, const int* in_sizes, int n_in,
                              void* d_out, int out_size, void* d_ws, size_t ws_size,
                              hipStream_t stream) {
    const float* logits  = (const float*)d_in[0];
    const int*   targets = (const int*)d_in[1];
    const float* gm      = (const float*)d_in[2];
    float* out = (float*)d_out;

    const int n = in_sizes[1];  // number of rows / targets

    float* ce = (float*)d_ws;   // n floats, fully overwritten every call

    ce_kernel<<<(n + 3) / 4, 256, 0, stream>>>(logits, targets, ce, n);
    finalize_kernel<<<1, 1024, 0, stream>>>(targets, ce, gm, out, n);
}

// Round 8
// 55.053 us; speedup vs baseline: 3.7720x; 3.7720x over previous
//
#include <hip/hip_runtime.h>
#include <math.h>

#define NUM_C   1000
#define MOM     0.9f
#define EPS     1e-6f
#define RBLK    32        // stage-2 reduce blocks
#define PSTRIDE 2048      // per-block partial stride (1000 sums @0, 1000 counts @1024)

// ---------------- kernel 1: per-row CE -> ce[row] ----------------
// Proven ~roofline (~38us, R7): two-pass from registers, pure store back-end,
// no memset dependency. DO NOT TOUCH (R4/R5/R6: online-softmax, no-max,
// 2-row ILP all regressed; R3: __threadfence fusion = 30x disaster).
__global__ __launch_bounds__(256) void ce_kernel(const float* __restrict__ logits,
                                                 const int*   __restrict__ targets,
                                                 float* __restrict__ ce,
                                                 int n) {
    const int wave = threadIdx.x >> 6;
    const int lane = threadIdx.x & 63;
    const int row  = blockIdx.x * 4 + wave;
    if (row >= n) return;

    const int t  = targets[row];        // wave-uniform -> one line, broadcast
    const int tq = t >> 2;              // float4 index holding the target
    const int tc = t & 3;

    const float4* rp = reinterpret_cast<const float4*>(logits + (size_t)row * NUM_C);

    float4 v[4];
    float m = -INFINITY;
#pragma unroll
    for (int j = 0; j < 4; ++j) {
        int idx = j * 64 + lane;
        if (idx < 250) {
            v[j] = rp[idx];
            m = fmaxf(m, fmaxf(fmaxf(v[j].x, v[j].y), fmaxf(v[j].z, v[j].w)));
        }
    }
#pragma unroll
    for (int off = 32; off > 0; off >>= 1)
        m = fmaxf(m, __shfl_xor(m, off, 64));

    float s = 0.f, lt = 0.f;
#pragma unroll
    for (int j = 0; j < 4; ++j) {
        int idx = j * 64 + lane;
        if (idx < 250) {
            s += __expf(v[j].x - m);
            s += __expf(v[j].y - m);
            s += __expf(v[j].z - m);
            s += __expf(v[j].w - m);
            if (idx == tq) {
                lt = (tc == 0) ? v[j].x : (tc == 1) ? v[j].y
                   : (tc == 2) ? v[j].z : v[j].w;
            }
        }
    }
#pragma unroll
    for (int off = 32; off > 0; off >>= 1) {
        s  += __shfl_xor(s,  off, 64);
        lt += __shfl_xor(lt, off, 64);
    }

    if (lane == 0)
        ce[row] = (m + __logf(s)) - lt;   // -log_softmax at target
}

// ---------------- kernel 2: partial segment-reduce (32 blocks) ----------------
// Block b accumulates rows [b*n/RBLK, (b+1)*n/RBLK) into LDS (atomics spread
// over 32 CUs — R7 lesson: 1-block LDS-atomic reduce = 167us), then writes its
// 2000-float partial to ws (coalesced; every slot later read is written).
__global__ __launch_bounds__(1024) void reduce_kernel(const int*   __restrict__ targets,
                                                      const float* __restrict__ ce,
                                                      float* __restrict__ partials,
                                                      int n) {
    __shared__ float ls[NUM_C];
    __shared__ float lc[NUM_C];
    for (int c = threadIdx.x; c < NUM_C; c += 1024) { ls[c] = 0.f; lc[c] = 0.f; }
    __syncthreads();

    const int per  = n / RBLK;                       // 2048 for n=65536
    const int base = blockIdx.x * per;
    const int end  = (blockIdx.x == RBLK - 1) ? n : base + per;
    for (int i = base + threadIdx.x; i < end; i += 1024) {
        int   t = targets[i];
        float c = ce[i];
        atomicAdd(&ls[t], c);
        atomicAdd(&lc[t], 1.0f);
    }
    __syncthreads();

    float* p = partials + (size_t)blockIdx.x * PSTRIDE;
    for (int c = threadIdx.x; c < NUM_C; c += 1024) {
        p[c]        = ls[c];
        p[c + 1024] = lc[c];
    }
}

// ---------------- kernel 3: combine + EMA + weighted ratio ----------------
// Thread c sums P[b][c] over b (coalesced at fixed b), then:
//   out = [sum_c s_c * w_c] / [sum_c cnt_c * w_c],  w_c = 1/(gm'_c + eps)
__global__ __launch_bounds__(1024) void final_kernel(const float* __restrict__ partials,
                                                     const float* __restrict__ gm_in,
                                                     float* __restrict__ out) {
    const int c = threadIdx.x;
    float a = 0.f, b = 0.f;
    if (c < NUM_C) {
        float s = 0.f, cnt = 0.f;
        for (int blk = 0; blk < RBLK; ++blk) {
            const float* p = partials + (size_t)blk * PSTRIDE;
            s   += p[c];
            cnt += p[c + 1024];
        }
        float g = gm_in[c];
        if (cnt > 0.f) {
            float cm = fabsf(s / fmaxf(cnt, 1.0f));
            g = MOM * g + (1.0f - MOM) * cm;
        }
        float w = 1.0f / (g + EPS);
        a = cnt * w;
        b = s * w;
    }
#pragma unroll
    for (int off = 32; off > 0; off >>= 1) {
        a += __shfl_xor(a, off, 64);
        b += __shfl_xor(b, off, 64);
    }
    __shared__ float sa[16], sb[16];
    const int lane = threadIdx.x & 63;
    const int wv   = threadIdx.x >> 6;
    if (lane == 0) { sa[wv] = a; sb[wv] = b; }
    __syncthreads();
    if (threadIdx.x == 0) {
        float A = 0.f, B = 0.f;
        for (int i = 0; i < 16; ++i) { A += sa[i]; B += sb[i]; }
        out[0] = B / A;
    }
}

extern "C" void kernel_launch(void* const* d_in, const int* in_sizes, int n_in,
                              void* d_out, int out_size, void* d_ws, size_t ws_size,
                              hipStream_t stream) {
    const float* logits  = (const float*)d_in[0];
    const int*   targets = (const int*)d_in[1];
    const float* gm      = (const float*)d_in[2];
    float* out = (float*)d_out;

    const int n = in_sizes[1];  // number of rows / targets

    float* ce       = (float*)d_ws;        // n floats
    float* partials = ce + n;              // RBLK * PSTRIDE floats (256 KB)

    ce_kernel<<<(n + 3) / 4, 256, 0, stream>>>(logits, targets, ce, n);
    reduce_kernel<<<RBLK, 1024, 0, stream>>>(targets, ce, partials, n);
    final_kernel<<<1, 1024, 0, stream>>>(partials, gm, out);
}